// Round 1
// baseline (248926.978 us; speedup 1.0000x reference)
//
#include <hip/hip_runtime.h>

// Encoder: 3-layer "bidirectional" LSTM (both dirs scan forward, per reference),
// H=256, B=64, T=1024, then per-timestep 256->81 linear + argmax (softmax is monotone).
//
// Strategy R1 (correctness-first):
//  - transpose x -> xT[t][k][b] (lane=b coalesced)
//  - persistent kernel, 512 blocks x 256 thr (2 blocks/CU via launch_bounds),
//    block=(dir,u), threads = 64 b-lanes x 4 K-chunks, LDS reduce, fused activations.
//    Hand-rolled flag-based grid barrier between the 3 layer stages per timestep.
//    h double-buffered across steps; c block-private (in-place).
//  - ys (layer2,dir1) stored transposed [t][b][u]; final kernel: conv81 + argmax -> int32 out[b*T+t].

#define H_ 256
#define B_ 64
#define T_ 1024
#define NBLK 512

// ws byte offsets
#define OFF_ARR 256
#define OFF_HA  8192
#define OFF_HB  401408
#define OFF_C   794624
#define OFF_XT  1187840
#define OFF_YS  17965056
// total ws use: 85,073,920 bytes

__device__ __forceinline__ float sigf(float x) {
  return 1.0f / (1.0f + __expf(-x));
}
__device__ __forceinline__ float tanhf_(float x) {
  float e = __expf(-2.0f * fabsf(x));
  float r = (1.0f - e) / (1.0f + e);
  return x >= 0.0f ? r : -r;
}

// ---------------- x transpose: x[b][k][t] -> xT[t][k][b] ----------------
__global__ __launch_bounds__(64) void transpose_x(const float* __restrict__ x,
                                                  float* __restrict__ xT) {
  __shared__ float tile[64][65];  // +1 pad: conflict-free column read
  const int k = blockIdx.y;        // 0..63 (input feature)
  const int t0 = blockIdx.x * 64;  // t tile
  const int lane = threadIdx.x;    // 0..63
  for (int bi = 0; bi < 64; ++bi)
    tile[bi][lane] = x[bi * 65536 + k * 1024 + t0 + lane];  // coalesced over t
  __syncthreads();
  for (int ti = 0; ti < 64; ++ti)
    xT[(t0 + ti) * 4096 + k * 64 + lane] = tile[lane][ti];  // coalesced over b
}

// ---------------- grid barrier (flag-based, agent scope) ----------------
__device__ __forceinline__ void grid_barrier(unsigned* __restrict__ gen,
                                             unsigned* __restrict__ arrive,
                                             unsigned target, int bb, int tid) {
  __syncthreads();
  if (bb == 0) {
    if (tid < 64) {
      for (int j = 1 + tid; j < NBLK; j += 64) {
        while (__hip_atomic_load(&arrive[j], __ATOMIC_ACQUIRE,
                                 __HIP_MEMORY_SCOPE_AGENT) < target) {
          __builtin_amdgcn_s_sleep(2);
        }
      }
    }
    __syncthreads();
    if (tid == 0) {
      __threadfence();
      __hip_atomic_store(gen, target, __ATOMIC_RELEASE, __HIP_MEMORY_SCOPE_AGENT);
    }
    __syncthreads();
  } else {
    if (tid == 0) {
      __threadfence();
      __hip_atomic_store(&arrive[bb], target, __ATOMIC_RELEASE,
                         __HIP_MEMORY_SCOPE_AGENT);
      while (__hip_atomic_load(gen, __ATOMIC_ACQUIRE,
                               __HIP_MEMORY_SCOPE_AGENT) < target) {
        __builtin_amdgcn_s_sleep(2);
      }
      __threadfence();
    }
    __syncthreads();
  }
}

// ---------------- gate reduce + activations + state update ----------------
__device__ __forceinline__ void gate_finish(int tid, float a0, float a1, float a2,
                                            float a3,
                                            const float* __restrict__ bias,
                                            float* __restrict__ cRow,
                                            float* __restrict__ hRow,
                                            float* __restrict__ ysRow,
                                            float (*red)[4][64]) {
  const int lane = tid & 63, kc = tid >> 6;
  red[kc][0][lane] = a0;
  red[kc][1][lane] = a1;
  red[kc][2][lane] = a2;
  red[kc][3][lane] = a3;
  __syncthreads();
  if (tid < 64) {
    float gi = ((red[0][0][tid] + red[1][0][tid]) + (red[2][0][tid] + red[3][0][tid])) + bias[0];
    float gf = ((red[0][1][tid] + red[1][1][tid]) + (red[2][1][tid] + red[3][1][tid])) + bias[256];
    float gg = ((red[0][2][tid] + red[1][2][tid]) + (red[2][2][tid] + red[3][2][tid])) + bias[512];
    float go = ((red[0][3][tid] + red[1][3][tid]) + (red[2][3][tid] + red[3][3][tid])) + bias[768];
    float iv = sigf(gi), fv = sigf(gf), gv = tanhf_(gg), ov = sigf(go);
    float c = fv * cRow[tid] + iv * gv;
    cRow[tid] = c;
    float h = ov * tanhf_(c);
    hRow[tid] = h;
    if (ysRow) ysRow[tid * H_] = h;  // ys[t][b][u], stride H_ over b
  }
}

// ---------------- big LSTM cell: K = 512 (inp concat) + 256 (rec) ----------------
__device__ __forceinline__ void cell768(int tid, int u,
                                        const float* __restrict__ inp0,
                                        const float* __restrict__ inp1,
                                        const float* __restrict__ rec,
                                        const float* __restrict__ wi,
                                        const float* __restrict__ wh,
                                        const float* __restrict__ bias,
                                        float* __restrict__ cRow,
                                        float* __restrict__ hRow,
                                        float* __restrict__ ysRow,
                                        float (*red)[4][64]) {
  const int lane = tid & 63, kc = tid >> 6;
  float a0 = 0.f, a1 = 0.f, a2 = 0.f, a3 = 0.f;
  const int lo = kc * 192, hi = lo + 192;
  const float* w0 = wi + (0 * H_ + u) * 512;
  const float* w1 = wi + (1 * H_ + u) * 512;
  const float* w2 = wi + (2 * H_ + u) * 512;
  const float* w3 = wi + (3 * H_ + u) * 512;
  // seg0: virtual k in [lo, min(hi,256)) from inp0
  {
    const int e = hi < 256 ? hi : 256;
    for (int k = lo; k < e; k += 4) {
      float4 q0 = *(const float4*)(w0 + k);
      float4 q1 = *(const float4*)(w1 + k);
      float4 q2 = *(const float4*)(w2 + k);
      float4 q3 = *(const float4*)(w3 + k);
      const float* ip = inp0 + k * 64 + lane;
      float v0 = ip[0], v1 = ip[64], v2 = ip[128], v3 = ip[192];
      a0 += q0.x * v0 + q0.y * v1 + q0.z * v2 + q0.w * v3;
      a1 += q1.x * v0 + q1.y * v1 + q1.z * v2 + q1.w * v3;
      a2 += q2.x * v0 + q2.y * v1 + q2.z * v2 + q2.w * v3;
      a3 += q3.x * v0 + q3.y * v1 + q3.z * v2 + q3.w * v3;
    }
  }
  // seg1: [max(lo,256), min(hi,512)) from inp1
  {
    const int s = lo > 256 ? lo : 256;
    const int e = hi < 512 ? hi : 512;
    for (int k = s; k < e; k += 4) {
      float4 q0 = *(const float4*)(w0 + k);
      float4 q1 = *(const float4*)(w1 + k);
      float4 q2 = *(const float4*)(w2 + k);
      float4 q3 = *(const float4*)(w3 + k);
      const float* ip = inp1 + (k - 256) * 64 + lane;
      float v0 = ip[0], v1 = ip[64], v2 = ip[128], v3 = ip[192];
      a0 += q0.x * v0 + q0.y * v1 + q0.z * v2 + q0.w * v3;
      a1 += q1.x * v0 + q1.y * v1 + q1.z * v2 + q1.w * v3;
      a2 += q2.x * v0 + q2.y * v1 + q2.z * v2 + q2.w * v3;
      a3 += q3.x * v0 + q3.y * v1 + q3.z * v2 + q3.w * v3;
    }
  }
  // seg2: [max(lo,512), hi) recurrent, wh rows
  {
    const int s = lo > 512 ? lo : 512;
    const int e = hi;
    const float* r0 = wh + (0 * H_ + u) * 256;
    const float* r1 = wh + (1 * H_ + u) * 256;
    const float* r2 = wh + (2 * H_ + u) * 256;
    const float* r3 = wh + (3 * H_ + u) * 256;
    for (int k = s; k < e; k += 4) {
      const int k2 = k - 512;
      float4 q0 = *(const float4*)(r0 + k2);
      float4 q1 = *(const float4*)(r1 + k2);
      float4 q2 = *(const float4*)(r2 + k2);
      float4 q3 = *(const float4*)(r3 + k2);
      const float* ip = rec + k2 * 64 + lane;
      float v0 = ip[0], v1 = ip[64], v2 = ip[128], v3 = ip[192];
      a0 += q0.x * v0 + q0.y * v1 + q0.z * v2 + q0.w * v3;
      a1 += q1.x * v0 + q1.y * v1 + q1.z * v2 + q1.w * v3;
      a2 += q2.x * v0 + q2.y * v1 + q2.z * v2 + q2.w * v3;
      a3 += q3.x * v0 + q3.y * v1 + q3.z * v2 + q3.w * v3;
    }
  }
  gate_finish(tid, a0, a1, a2, a3, bias, cRow, hRow, ysRow, red);
}

// ---------------- persistent LSTM kernel ----------------
__global__ __launch_bounds__(256, 2) void lstm_persistent(
    const float* __restrict__ Wih0, const float* __restrict__ Whh0,
    const float* __restrict__ b0, const float* __restrict__ Wih12,
    const float* __restrict__ Whh12, const float* __restrict__ b12, char* wsb) {
  unsigned* gen = (unsigned*)wsb;
  unsigned* arrive = (unsigned*)(wsb + OFF_ARR);
  float* hA = (float*)(wsb + OFF_HA);
  float* hB = (float*)(wsb + OFF_HB);
  float* cT = (float*)(wsb + OFF_C);
  const float* xT = (const float*)(wsb + OFF_XT);
  float* ys = (float*)(wsb + OFF_YS);

  __shared__ float red[4][4][64];

  const int bb = blockIdx.x;  // 0..511
  const int tid = threadIdx.x;
  const int lane = tid & 63;
  const int kc = tid >> 6;
  const int d = bb >> 8;  // direction 0/1
  const int u = bb & 255; // hidden unit

  unsigned phase = 0;

  for (int t = 0; t < T_; ++t) {
    const float* hR = (t & 1) ? hB : hA;  // previous-step states
    float* hW = (t & 1) ? hA : hB;        // this-step states

    // ---- Layer 0 (cell idx = d): K = 64 (x) + 256 (rec) split 4x80 ----
    {
      const float* xt = xT + t * (64 * B_);
      const float* wi = Wih0 + d * (1024 * 64);
      const float* wh = Whh0 + d * (1024 * 256);
      float a0 = 0.f, a1 = 0.f, a2 = 0.f, a3 = 0.f;
      const int lo = kc * 80, hi = lo + 80;
      {  // x part
        const int e = hi < 64 ? hi : 64;
        const float* p0 = wi + (0 * H_ + u) * 64;
        const float* p1 = wi + (1 * H_ + u) * 64;
        const float* p2 = wi + (2 * H_ + u) * 64;
        const float* p3 = wi + (3 * H_ + u) * 64;
        for (int k = lo; k < e; k += 4) {
          float4 q0 = *(const float4*)(p0 + k);
          float4 q1 = *(const float4*)(p1 + k);
          float4 q2 = *(const float4*)(p2 + k);
          float4 q3 = *(const float4*)(p3 + k);
          const float* ip = xt + k * 64 + lane;
          float v0 = ip[0], v1 = ip[64], v2 = ip[128], v3 = ip[192];
          a0 += q0.x * v0 + q0.y * v1 + q0.z * v2 + q0.w * v3;
          a1 += q1.x * v0 + q1.y * v1 + q1.z * v2 + q1.w * v3;
          a2 += q2.x * v0 + q2.y * v1 + q2.z * v2 + q2.w * v3;
          a3 += q3.x * v0 + q3.y * v1 + q3.z * v2 + q3.w * v3;
        }
      }
      {  // h part
        const int s = (lo > 64 ? lo : 64) - 64;
        const int e = hi - 64;
        const float* hp = hR + d * (H_ * B_);
        const float* p0 = wh + (0 * H_ + u) * 256;
        const float* p1 = wh + (1 * H_ + u) * 256;
        const float* p2 = wh + (2 * H_ + u) * 256;
        const float* p3 = wh + (3 * H_ + u) * 256;
        for (int k = s; k < e; k += 4) {
          float4 q0 = *(const float4*)(p0 + k);
          float4 q1 = *(const float4*)(p1 + k);
          float4 q2 = *(const float4*)(p2 + k);
          float4 q3 = *(const float4*)(p3 + k);
          const float* ip = hp + k * 64 + lane;
          float v0 = ip[0], v1 = ip[64], v2 = ip[128], v3 = ip[192];
          a0 += q0.x * v0 + q0.y * v1 + q0.z * v2 + q0.w * v3;
          a1 += q1.x * v0 + q1.y * v1 + q1.z * v2 + q1.w * v3;
          a2 += q2.x * v0 + q2.y * v1 + q2.z * v2 + q2.w * v3;
          a3 += q3.x * v0 + q3.y * v1 + q3.z * v2 + q3.w * v3;
        }
      }
      gate_finish(tid, a0, a1, a2, a3, b0 + d * 1024 + u,
                  cT + d * (H_ * B_) + u * 64, hW + d * (H_ * B_) + u * 64,
                  nullptr, red);
    }
    ++phase;
    grid_barrier(gen, arrive, phase, bb, tid);

    // ---- Layer 1 (cell idx = 2+d): inp = hW[0..1], rec = hR[2+d] ----
    cell768(tid, u, hW + 0 * (H_ * B_), hW + 1 * (H_ * B_),
            hR + (2 + d) * (H_ * B_), Wih12 + d * (1024 * 512),
            Whh12 + d * (1024 * 256), b12 + d * 1024 + u,
            cT + (2 + d) * (H_ * B_) + u * 64,
            hW + (2 + d) * (H_ * B_) + u * 64, nullptr, red);
    ++phase;
    grid_barrier(gen, arrive, phase, bb, tid);

    // ---- Layer 2 (cell idx = 4+d): inp = hW[2..3], rec = hR[4+d] ----
    cell768(tid, u, hW + 2 * (H_ * B_), hW + 3 * (H_ * B_),
            hR + (4 + d) * (H_ * B_), Wih12 + (2 + d) * (1024 * 512),
            Whh12 + (2 + d) * (1024 * 256), b12 + (2 + d) * 1024 + u,
            cT + (4 + d) * (H_ * B_) + u * 64,
            hW + (4 + d) * (H_ * B_) + u * 64,
            (d == 1) ? (ys + t * (H_ * B_) + u) : nullptr, red);
    ++phase;
    grid_barrier(gen, arrive, phase, bb, tid);
  }
}

// ---------------- conv(256->81) + argmax ----------------
__global__ __launch_bounds__(256) void conv_argmax(const float* __restrict__ yst,
                                                   const float* __restrict__ cw,
                                                   const float* __restrict__ cb,
                                                   int* __restrict__ out) {
  const int t = blockIdx.x;
  const int tid = threadIdx.x, lane = tid & 63, w = tid >> 6;
  const float* yrow = yst + t * (B_ * H_) + lane * H_;  // ys[t][b=lane][*]
  float best = -3.4e38f;
  int bi = 0;
  for (int og = 0; og < 3; ++og) {
    float acc[8];
    int ov[8];
#pragma unroll
    for (int m = 0; m < 8; ++m) {
      int o = w + 32 * og + 4 * m;
      ov[m] = (o < 81) ? o : 80;  // clamp row for safe loads
      acc[m] = (o < 81) ? cb[o] : -3.4e38f;
    }
    for (int uu = 0; uu < H_; uu += 4) {
      float4 y4 = *(const float4*)(yrow + uu);
#pragma unroll
      for (int m = 0; m < 8; ++m) {
        const float* wr = cw + ov[m] * H_ + uu;
        acc[m] += wr[0] * y4.x + wr[1] * y4.y + wr[2] * y4.z + wr[3] * y4.w;
      }
    }
#pragma unroll
    for (int m = 0; m < 8; ++m) {
      int o = w + 32 * og + 4 * m;
      if (o < 81 && acc[m] > best) {  // o ascending: strict > keeps first max
        best = acc[m];
        bi = o;
      }
    }
  }
  __shared__ float sv[4][64];
  __shared__ int si[4][64];
  sv[w][lane] = best;
  si[w][lane] = bi;
  __syncthreads();
  if (tid < 64) {
    float bv = sv[0][tid];
    int bo = si[0][tid];
#pragma unroll
    for (int ww = 1; ww < 4; ++ww) {
      float v = sv[ww][tid];
      int o = si[ww][tid];
      if (v > bv || (v == bv && o < bo)) {
        bv = v;
        bo = o;
      }
    }
    out[tid * T_ + t] = bo;  // out[b*T + t]
  }
}

extern "C" void kernel_launch(void* const* d_in, const int* in_sizes, int n_in,
                              void* d_out, int out_size, void* d_ws,
                              size_t ws_size, hipStream_t stream) {
  const float* x = (const float*)d_in[0];
  const float* Wih0 = (const float*)d_in[1];
  const float* Whh0 = (const float*)d_in[2];
  const float* b0 = (const float*)d_in[3];
  const float* Wih12 = (const float*)d_in[4];
  const float* Whh12 = (const float*)d_in[5];
  const float* b12 = (const float*)d_in[6];
  const float* cw = (const float*)d_in[7];
  const float* cb = (const float*)d_in[8];
  int* out = (int*)d_out;
  char* wsb = (char*)d_ws;

  // zero barrier flags + hA + hB + cT (ws is poisoned 0xAA before every launch)
  hipMemsetAsync(wsb, 0, OFF_XT, stream);
  transpose_x<<<dim3(16, 64, 1), dim3(64, 1, 1), 0, stream>>>(
      x, (float*)(wsb + OFF_XT));
  lstm_persistent<<<dim3(NBLK, 1, 1), dim3(256, 1, 1), 0, stream>>>(
      Wih0, Whh0, b0, Wih12, Whh12, b12, wsb);
  conv_argmax<<<dim3(T_, 1, 1), dim3(256, 1, 1), 0, stream>>>(
      (const float*)(wsb + OFF_YS), cw, cb, out);
}

// Round 2
// 51109.048 us; speedup vs baseline: 4.8705x; 4.8705x over previous
//
#include <hip/hip_runtime.h>

// Encoder: 3-layer bidirectional-weights LSTM (both dirs scan forward per the
// reference), H=256, B=64, T=1024, then 256->81 linear + argmax (softmax is
// monotone -> dead code).
//
// R2: skewed pipeline (layer l computes t=tick-l), ONE grid barrier per tick
// (1026 ticks), relaxed-spin hierarchical counter barrier (no per-iteration
// buffer_inv), 256 blocks x 1024 threads (1/CU), u-tile=2 (8 acc per act load),
// c-state in LDS (fence-immune), h ring double-buffered in ws.

#define H_ 256
#define B_ 64
#define T_ 1024
#define NBLK 256
#define NTHR 1024
#define NW 16          // waves per block
#define HBUF 98304     // floats per h ring buffer: 6 cells * 256u * 64b
#define NTICK 1026

// ws byte offsets
#define OFF_GEN  0
#define OFF_ROOT 64
#define OFF_CNT  128          // 8 counters, 64B apart (through 640)
#define OFF_H    4096         // hbuf[2][6][256*64] floats = 786432 B
#define OFF_XT   1048576      // xT[1024][64][64] floats = 16 MB
#define OFF_YS   17825792     // ys[1024][64][256] floats = 64 MB (ends 84,934,656)

__device__ __forceinline__ float sigf(float x) {
  return 1.0f / (1.0f + __expf(-x));
}
__device__ __forceinline__ float tanhf_(float x) {
  float e = __expf(-2.0f * fabsf(x));
  float r = (1.0f - e) / (1.0f + e);
  return x >= 0.0f ? r : -r;
}

// ---------------- x transpose: x[b][k][t] -> xT[t][k][b] ----------------
__global__ __launch_bounds__(64) void transpose_x(const float* __restrict__ x,
                                                  float* __restrict__ xT) {
  __shared__ float tile[64][65];
  const int k = blockIdx.y;
  const int t0 = blockIdx.x * 64;
  const int lane = threadIdx.x;
  for (int bi = 0; bi < 64; ++bi)
    tile[bi][lane] = x[bi * 65536 + k * 1024 + t0 + lane];
  __syncthreads();
  for (int ti = 0; ti < 64; ++ti)
    xT[(t0 + ti) * 4096 + k * 64 + lane] = tile[lane][ti];
}

// ---------------- one (cell, u0..u0+1) gate task ----------------
// 3 activation segments; global k in [0, n0+n1+n2), wave w owns slice of K/NW.
// acc r = uu*4+g  -> weight row = g*256 + u0 + uu  (uu = r>>2, g = r&3)
__device__ __forceinline__ void run_task(
    int tid, int u0,
    const float* __restrict__ a0, const float* __restrict__ w0, int rs0, int n0,
    const float* __restrict__ a1, const float* __restrict__ w1, int rs1, int n1,
    const float* __restrict__ a2, const float* __restrict__ w2, int rs2, int n2,
    const float* __restrict__ bias, float* __restrict__ cst,  // cst[2*64]
    float* __restrict__ hout,                                  // Wbuf + cell*16384
    float* __restrict__ ysrow,                                 // ys + t*16384 or null
    float (*red)[8][64]) {
  const int w = tid >> 6, lane = tid & 63;
  const int K = n0 + n1 + n2;
  const int KW = K / NW;
  const int lo = w * KW, hi = lo + KW;
  float acc[8] = {0.f, 0.f, 0.f, 0.f, 0.f, 0.f, 0.f, 0.f};

  // seg0: global k in [0, n0)
  {
    const int a = lo;
    const int b = hi < n0 ? hi : n0;
#pragma unroll 2
    for (int k = a; k < b; k += 4) {
      const float* ip = a0 + k * 64 + lane;
      float v0 = ip[0], v1 = ip[64], v2 = ip[128], v3 = ip[192];
#pragma unroll
      for (int r = 0; r < 8; ++r) {
        float4 q = *(const float4*)(w0 + ((size_t)((r & 3) * 256 + u0 + (r >> 2))) * rs0 + k);
        acc[r] += q.x * v0 + q.y * v1 + q.z * v2 + q.w * v3;
      }
    }
  }
  // seg1: global k in [n0, n0+n1)
  {
    const int s1 = n0, e1 = n0 + n1;
    const int a = lo > s1 ? lo : s1;
    const int b = hi < e1 ? hi : e1;
#pragma unroll 2
    for (int k = a; k < b; k += 4) {
      const int kk = k - s1;
      const float* ip = a1 + kk * 64 + lane;
      float v0 = ip[0], v1 = ip[64], v2 = ip[128], v3 = ip[192];
#pragma unroll
      for (int r = 0; r < 8; ++r) {
        float4 q = *(const float4*)(w1 + ((size_t)((r & 3) * 256 + u0 + (r >> 2))) * rs1 + kk);
        acc[r] += q.x * v0 + q.y * v1 + q.z * v2 + q.w * v3;
      }
    }
  }
  // seg2: global k in [n0+n1, K)
  if (n2) {
    const int s2 = n0 + n1;
    const int a = lo > s2 ? lo : s2;
    const int b = hi;
#pragma unroll 2
    for (int k = a; k < b; k += 4) {
      const int kk = k - s2;
      const float* ip = a2 + kk * 64 + lane;
      float v0 = ip[0], v1 = ip[64], v2 = ip[128], v3 = ip[192];
#pragma unroll
      for (int r = 0; r < 8; ++r) {
        float4 q = *(const float4*)(w2 + ((size_t)((r & 3) * 256 + u0 + (r >> 2))) * rs2 + kk);
        acc[r] += q.x * v0 + q.y * v1 + q.z * v2 + q.w * v3;
      }
    }
  }

#pragma unroll
  for (int r = 0; r < 8; ++r) red[w][r][lane] = acc[r];
  __syncthreads();
  if (tid < 128) {
    const int uu = tid >> 6, b = tid & 63;
    float gi = bias[0 * 256 + u0 + uu];
    float gf = bias[1 * 256 + u0 + uu];
    float gg = bias[2 * 256 + u0 + uu];
    float go = bias[3 * 256 + u0 + uu];
#pragma unroll
    for (int ww = 0; ww < NW; ++ww) {
      gi += red[ww][uu * 4 + 0][b];
      gf += red[ww][uu * 4 + 1][b];
      gg += red[ww][uu * 4 + 2][b];
      go += red[ww][uu * 4 + 3][b];
    }
    float iv = sigf(gi), fv = sigf(gf), gv = tanhf_(gg), ov = sigf(go);
    float c = fv * cst[uu * 64 + b] + iv * gv;
    cst[uu * 64 + b] = c;
    float h = ov * tanhf_(c);
    hout[(u0 + uu) * 64 + b] = h;
    if (ysrow) ysrow[b * 256 + u0 + uu] = h;
  }
  __syncthreads();
}

// ---------------- persistent skewed LSTM ----------------
__global__ __launch_bounds__(NTHR, 1) void lstm_persistent(
    const float* __restrict__ Wih0, const float* __restrict__ Whh0,
    const float* __restrict__ b0, const float* __restrict__ Wih12,
    const float* __restrict__ Whh12, const float* __restrict__ b12, char* wsb) {
  unsigned* gen = (unsigned*)(wsb + OFF_GEN);
  unsigned* root = (unsigned*)(wsb + OFF_ROOT);
  float* hb = (float*)(wsb + OFF_H);
  const float* xT = (const float*)(wsb + OFF_XT);
  float* ys = (float*)(wsb + OFF_YS);

  __shared__ float red[NW][8][64];     // 32 KB
  __shared__ float cst[3][2][64];      // per-layer c state (fence-immune)

  const int bb = blockIdx.x;
  const int tid = threadIdx.x;
  const int d = bb >> 7;         // direction 0/1
  const int u0 = (bb & 127) * 2; // u tile base

  if (tid < 384) ((float*)cst)[tid] = 0.f;
  __syncthreads();

  unsigned* mycnt = (unsigned*)(wsb + OFF_CNT + (size_t)(bb & 7) * 64);

  for (unsigned tick = 0; tick < NTICK; ++tick) {
    const float* R = hb + ((tick + 1) & 1) * HBUF;  // produced last tick
    float* W = hb + (tick & 1) * HBUF;              // produced this tick

    // Layer 0 (cell d): t = tick; K = 64 (x) + 256 (rec)
    if (tick < 1024) {
      run_task(tid, u0,
               xT + (size_t)tick * 4096, Wih0 + (size_t)d * (1024 * 64), 64, 64,
               R + (size_t)d * 16384, Whh0 + (size_t)d * (1024 * 256), 256, 256,
               nullptr, nullptr, 0, 0,
               b0 + d * 1024, &cst[0][0][0], W + (size_t)d * 16384, nullptr, red);
    }
    // Layer 1 (cell 2+d): t = tick-1; K = 256+256 (inp concat) + 256 (rec)
    if (tick >= 1 && tick < 1025) {
      run_task(tid, u0,
               R + (size_t)0 * 16384, Wih12 + (size_t)d * (1024 * 512), 512, 256,
               R + (size_t)1 * 16384, Wih12 + (size_t)d * (1024 * 512) + 256, 512, 256,
               R + (size_t)(2 + d) * 16384, Whh12 + (size_t)d * (1024 * 256), 256, 256,
               b12 + d * 1024, &cst[1][0][0], W + (size_t)(2 + d) * 16384, nullptr,
               red);
    }
    // Layer 2 (cell 4+d): t = tick-2
    if (tick >= 2) {
      const int t = (int)tick - 2;
      run_task(tid, u0,
               R + (size_t)2 * 16384, Wih12 + (size_t)(2 + d) * (1024 * 512), 512, 256,
               R + (size_t)3 * 16384, Wih12 + (size_t)(2 + d) * (1024 * 512) + 256, 512, 256,
               R + (size_t)(4 + d) * 16384, Whh12 + (size_t)(2 + d) * (1024 * 256), 256, 256,
               b12 + (2 + d) * 1024, &cst[2][0][0], W + (size_t)(4 + d) * 16384,
               (d == 1) ? (ys + (size_t)t * 16384) : nullptr, red);
    }

    // -------- grid barrier: relaxed spin, hierarchical counter --------
    __syncthreads();  // block's stores drained (compiler emits vmcnt(0) pre-barrier)
    if (tid == 0) {
      __builtin_amdgcn_fence(__ATOMIC_RELEASE, "agent");  // publish h/ys (wbl2)
      unsigned old = __hip_atomic_fetch_add(mycnt, 1u, __ATOMIC_RELAXED,
                                            __HIP_MEMORY_SCOPE_AGENT);
      if (old == (tick + 1) * (NBLK / 8) - 1) {
        unsigned r = __hip_atomic_fetch_add(root, 1u, __ATOMIC_RELAXED,
                                            __HIP_MEMORY_SCOPE_AGENT);
        if (r == (tick + 1) * 8 - 1) {
          __hip_atomic_store(gen, tick + 1, __ATOMIC_RELAXED,
                             __HIP_MEMORY_SCOPE_AGENT);
        }
      }
      while (__hip_atomic_load(gen, __ATOMIC_RELAXED, __HIP_MEMORY_SCOPE_AGENT) <
             tick + 1) {
        __builtin_amdgcn_s_sleep(2);
      }
      __builtin_amdgcn_fence(__ATOMIC_ACQUIRE, "agent");  // invalidate stale L1/L2
    }
    __syncthreads();
  }
}

// ---------------- conv(256->81) + argmax ----------------
__global__ __launch_bounds__(256) void conv_argmax(const float* __restrict__ yst,
                                                   const float* __restrict__ cw,
                                                   const float* __restrict__ cb,
                                                   int* __restrict__ out) {
  const int t = blockIdx.x;
  const int tid = threadIdx.x, lane = tid & 63, w = tid >> 6;
  const float* yrow = yst + (size_t)t * (B_ * H_) + lane * H_;
  float best = -3.4e38f;
  int bi = 0;
  for (int og = 0; og < 3; ++og) {
    float acc[8];
    int ov[8];
#pragma unroll
    for (int m = 0; m < 8; ++m) {
      int o = w + 32 * og + 4 * m;
      ov[m] = (o < 81) ? o : 80;
      acc[m] = (o < 81) ? cb[o] : -3.4e38f;
    }
    for (int uu = 0; uu < H_; uu += 4) {
      float4 y4 = *(const float4*)(yrow + uu);
#pragma unroll
      for (int m = 0; m < 8; ++m) {
        const float* wr = cw + ov[m] * H_ + uu;
        acc[m] += wr[0] * y4.x + wr[1] * y4.y + wr[2] * y4.z + wr[3] * y4.w;
      }
    }
#pragma unroll
    for (int m = 0; m < 8; ++m) {
      int o = w + 32 * og + 4 * m;
      if (o < 81 && acc[m] > best) {
        best = acc[m];
        bi = o;
      }
    }
  }
  __shared__ float sv[4][64];
  __shared__ int si[4][64];
  sv[w][lane] = best;
  si[w][lane] = bi;
  __syncthreads();
  if (tid < 64) {
    float bv = sv[0][tid];
    int bo = si[0][tid];
#pragma unroll
    for (int ww = 1; ww < 4; ++ww) {
      float v = sv[ww][tid];
      int o = si[ww][tid];
      if (v > bv || (v == bv && o < bo)) {
        bv = v;
        bo = o;
      }
    }
    out[tid * T_ + t] = bo;
  }
}

extern "C" void kernel_launch(void* const* d_in, const int* in_sizes, int n_in,
                              void* d_out, int out_size, void* d_ws,
                              size_t ws_size, hipStream_t stream) {
  const float* x = (const float*)d_in[0];
  const float* Wih0 = (const float*)d_in[1];
  const float* Whh0 = (const float*)d_in[2];
  const float* b0 = (const float*)d_in[3];
  const float* Wih12 = (const float*)d_in[4];
  const float* Whh12 = (const float*)d_in[5];
  const float* b12 = (const float*)d_in[6];
  const float* cw = (const float*)d_in[7];
  const float* cb = (const float*)d_in[8];
  int* out = (int*)d_out;
  char* wsb = (char*)d_ws;

  // zero flags + h ring (ws is re-poisoned 0xAA before every launch)
  hipMemsetAsync(wsb, 0, OFF_H + 786432, stream);
  transpose_x<<<dim3(16, 64, 1), dim3(64, 1, 1), 0, stream>>>(
      x, (float*)(wsb + OFF_XT));
  lstm_persistent<<<dim3(NBLK, 1, 1), dim3(NTHR, 1, 1), 0, stream>>>(
      Wih0, Whh0, b0, Wih12, Whh12, b12, wsb);
  conv_argmax<<<dim3(T_, 1, 1), dim3(256, 1, 1), 0, stream>>>(
      (const float*)(wsb + OFF_YS), cw, cb, out);
}

// Round 4
// 25350.923 us; speedup vs baseline: 9.8192x; 2.0161x over previous
//
#include <hip/hip_runtime.h>

// Encoder: 3-layer bidirectional-weights LSTM (both dirs scan forward per the
// reference), H=256, B=64, T=1024, then 256->81 linear + argmax (softmax is
// monotone -> dead code).
//
// R4: R3 structure (scalar/uniform weight addressing, interleaved [k4][b][4]
// act layout, one float4 act load per k4, b128 LDS reduction) with R2's EXACT
// accumulation order restored (bit-identical numerics to the passing R2):
//  - one fma chain per gate row:  acc += qx*vx + qy*vy + qz*vz + qw*vw
//  - epilogue: gate = bias, then += 16 wave partials in ascending wave order
// (R3's 4-chain accumulation + bias-last flipped near-tie argmaxes: absmax 2.0)

#define H_ 256
#define B_ 64
#define T_ 1024
#define NBLK 256
#define NTHR 1024
#define HBUF 98304     // floats per h ring buffer: 6 cells * 16384
#define NTICK 1026

// ws byte offsets
#define OFF_GEN  0
#define OFF_ROOT 64
#define OFF_CNT  128          // 8 counters, 64B apart
#define OFF_H    4096         // hbuf[2][6][16384] floats = 786432 B
#define OFF_XT   1048576      // xT2[1024][16][64][4] floats = 16 MB
#define OFF_YS   17825792     // ys[1024][64][256] floats = 64 MB

__device__ __forceinline__ float sigf(float x) {
  return 1.0f / (1.0f + __expf(-x));
}
__device__ __forceinline__ float tanhf_(float x) {
  float e = __expf(-2.0f * fabsf(x));
  float r = (1.0f - e) / (1.0f + e);
  return x >= 0.0f ? r : -r;
}

// ---------------- x transpose: x[b][k][t] -> xT2[t][k>>2][b][k&3] ----------------
__global__ __launch_bounds__(64) void transpose_x(const float* __restrict__ x,
                                                  float* __restrict__ xT) {
  __shared__ float tile[64][65];
  const int k = blockIdx.y;
  const int t0 = blockIdx.x * 64;
  const int lane = threadIdx.x;  // = t on read, = b on write
  for (int bi = 0; bi < 64; ++bi)
    tile[bi][lane] = x[bi * 65536 + k * 1024 + t0 + lane];
  __syncthreads();
  for (int ti = 0; ti < 64; ++ti)
    xT[(size_t)(t0 + ti) * 4096 + (k >> 2) * 256 + lane * 4 + (k & 3)] =
        tile[lane][ti];
}

// ---------------- one gate task: 8 rows (2 units x 4 gates), K4 k4-groups ----
// a = uu*4 + g ; weight row = g*256 + u0 + uu ; act layout [k4][b][4]
__device__ __forceinline__ void task8(
    const int w, const int lane, const int tid, const int u0,
    const int K4, const int nA4,
    const float4* __restrict__ actA,   // k4 in [0, nA4)
    const float4* __restrict__ actB,   // k4 in [nA4, K4), indexed k4-nA4
    const float* __restrict__ wAb, const int wAs,
    const float* __restrict__ wBb, const int wBs,
    const float* __restrict__ bias,    // bias[g*256 + u]
    float* __restrict__ cst2,          // LDS [2][64]
    float* __restrict__ hcell,         // h write base for this cell
    float* __restrict__ ysrow,         // ys + t*16384 or nullptr
    float (*red)[64][12]) {
  const int slice = K4 >> 4;           // K4/16 waves
  const int lo = w * slice, hi = lo + slice;
  float acc[8] = {0.f, 0.f, 0.f, 0.f, 0.f, 0.f, 0.f, 0.f};

  // ---- segment A ----
  {
    const int b4 = hi < nA4 ? hi : nA4;
#pragma unroll 2
    for (int k4 = lo; k4 < b4; ++k4) {
      float4 av = actA[k4 * 64 + lane];
#pragma unroll
      for (int a = 0; a < 8; ++a) {
        const float* wp = wAb + (size_t)((a & 3) * 256 + u0 + (a >> 2)) * wAs + k4 * 4;
        float4 wq = *(const float4*)wp;
        acc[a] += wq.x * av.x + wq.y * av.y + wq.z * av.z + wq.w * av.w;
      }
    }
  }
  // ---- segment B ----
  {
    const int a4 = lo > nA4 ? lo : nA4;
#pragma unroll 2
    for (int k4 = a4; k4 < hi; ++k4) {
      const int kk = k4 - nA4;
      float4 av = actB[kk * 64 + lane];
#pragma unroll
      for (int a = 0; a < 8; ++a) {
        const float* wp = wBb + (size_t)((a & 3) * 256 + u0 + (a >> 2)) * wBs + kk * 4;
        float4 wq = *(const float4*)wp;
        acc[a] += wq.x * av.x + wq.y * av.y + wq.z * av.z + wq.w * av.w;
      }
    }
  }

  // 8 partials -> 2x b128 LDS writes
  float4 r0 = make_float4(acc[0], acc[1], acc[2], acc[3]);
  float4 r1 = make_float4(acc[4], acc[5], acc[6], acc[7]);
  *(float4*)&red[w][lane][0] = r0;
  *(float4*)&red[w][lane][4] = r1;
  __syncthreads();

  if (tid < 128) {
    const int uu = tid >> 6, b = tid & 63;
    // bias FIRST, then wave partials in ascending order (matches R2 bitwise)
    float gi = bias[0 * 256 + u0 + uu];
    float gf = bias[1 * 256 + u0 + uu];
    float gg = bias[2 * 256 + u0 + uu];
    float go = bias[3 * 256 + u0 + uu];
#pragma unroll
    for (int ww = 0; ww < 16; ++ww) {
      float4 s = *(const float4*)&red[ww][b][uu * 4];
      gi += s.x; gf += s.y; gg += s.z; go += s.w;
    }
    float iv = sigf(gi), fv = sigf(gf), gv = tanhf_(gg), ov = sigf(go);
    float c = fv * cst2[uu * 64 + b] + iv * gv;
    cst2[uu * 64 + b] = c;
    float h = ov * tanhf_(c);
    const int u = u0 + uu;
    hcell[(u >> 2) * 256 + b * 4 + (u & 3)] = h;
    if (ysrow) ysrow[b * 256 + u] = h;
  }
  __syncthreads();
}

// ---------------- persistent skewed LSTM ----------------
__global__ __launch_bounds__(NTHR, 1) void lstm_persistent(
    const float* __restrict__ Wih0, const float* __restrict__ Whh0,
    const float* __restrict__ b0, const float* __restrict__ Wih12,
    const float* __restrict__ Whh12, const float* __restrict__ b12, char* wsb) {
  unsigned* gen = (unsigned*)(wsb + OFF_GEN);
  unsigned* root = (unsigned*)(wsb + OFF_ROOT);
  float* hb = (float*)(wsb + OFF_H);
  const float* xT = (const float*)(wsb + OFF_XT);
  float* ys = (float*)(wsb + OFF_YS);

  __shared__ float red[16][64][12];   // 48 KB, b128-friendly (pad 12)
  __shared__ float cst[3][2][64];     // per-layer c state

  const int bid = blockIdx.x;
  const int tid = threadIdx.x;
  const int lane = tid & 63;
  const int w = __builtin_amdgcn_readfirstlane(tid >> 6);  // uniform wave id
  const int d = bid >> 7;          // direction 0/1
  const int u0 = (bid & 127) * 2;  // unit tile base

  if (tid < 384) ((float*)cst)[tid] = 0.f;
  __syncthreads();

  unsigned* mycnt = (unsigned*)(wsb + OFF_CNT + (size_t)(bid & 7) * 64);

  for (unsigned tick = 0; tick < NTICK; ++tick) {
    const float* R = hb + ((tick + 1) & 1) * HBUF;  // produced last tick
    float* W = hb + (tick & 1) * HBUF;              // produced this tick
    const float4* Rf4 = (const float4*)R;

    // Layer 0 (cell d): t = tick; K4 = 16 (x) + 64 (rec)
    if (tick < 1024) {
      task8(w, lane, tid, u0, 80, 16,
            (const float4*)xT + (size_t)tick * 1024,
            Rf4 + (size_t)d * 4096,
            Wih0 + (size_t)d * 65536, 64,
            Whh0 + (size_t)d * 262144, 256,
            b0 + d * 1024, &cst[0][0][0], W + (size_t)d * 16384, nullptr, red);
    }
    // Layer 1 (cell 2+d): t = tick-1; K4 = 128 (cells 0,1) + 64 (rec)
    if (tick >= 1 && tick < 1025) {
      task8(w, lane, tid, u0, 192, 128,
            Rf4,
            Rf4 + (size_t)(2 + d) * 4096,
            Wih12 + (size_t)d * 524288, 512,
            Whh12 + (size_t)d * 262144, 256,
            b12 + d * 1024, &cst[1][0][0], W + (size_t)(2 + d) * 16384, nullptr,
            red);
    }
    // Layer 2 (cell 4+d): t = tick-2; K4 = 128 (cells 2,3) + 64 (rec)
    if (tick >= 2) {
      const int t = (int)tick - 2;
      task8(w, lane, tid, u0, 192, 128,
            Rf4 + (size_t)2 * 4096,
            Rf4 + (size_t)(4 + d) * 4096,
            Wih12 + (size_t)(2 + d) * 524288, 512,
            Whh12 + (size_t)(2 + d) * 262144, 256,
            b12 + (2 + d) * 1024, &cst[2][0][0], W + (size_t)(4 + d) * 16384,
            (d == 1) ? (ys + (size_t)t * 16384) : nullptr, red);
    }

    // -------- grid barrier: relaxed spin, hierarchical counter --------
    __syncthreads();
    if (tid == 0) {
      __builtin_amdgcn_fence(__ATOMIC_RELEASE, "agent");  // publish h/ys
      unsigned old = __hip_atomic_fetch_add(mycnt, 1u, __ATOMIC_RELAXED,
                                            __HIP_MEMORY_SCOPE_AGENT);
      if (old == (tick + 1) * (NBLK / 8) - 1) {
        unsigned r = __hip_atomic_fetch_add(root, 1u, __ATOMIC_RELAXED,
                                            __HIP_MEMORY_SCOPE_AGENT);
        if (r == (tick + 1) * 8 - 1) {
          __hip_atomic_store(gen, tick + 1, __ATOMIC_RELAXED,
                             __HIP_MEMORY_SCOPE_AGENT);
        }
      }
      while (__hip_atomic_load(gen, __ATOMIC_RELAXED, __HIP_MEMORY_SCOPE_AGENT) <
             tick + 1) {
        __builtin_amdgcn_s_sleep(2);
      }
      __builtin_amdgcn_fence(__ATOMIC_ACQUIRE, "agent");  // see others' h
    }
    __syncthreads();
  }
}

// ---------------- conv(256->81) + argmax ----------------
__global__ __launch_bounds__(256) void conv_argmax(const float* __restrict__ yst,
                                                   const float* __restrict__ cw,
                                                   const float* __restrict__ cb,
                                                   int* __restrict__ out) {
  const int t = blockIdx.x;
  const int tid = threadIdx.x, lane = tid & 63, w = tid >> 6;
  const float* yrow = yst + (size_t)t * (B_ * H_) + lane * H_;
  float best = -3.4e38f;
  int bi = 0;
  for (int og = 0; og < 3; ++og) {
    float acc[8];
    int ov[8];
#pragma unroll
    for (int m = 0; m < 8; ++m) {
      int o = w + 32 * og + 4 * m;
      ov[m] = (o < 81) ? o : 80;
      acc[m] = (o < 81) ? cb[o] : -3.4e38f;
    }
    for (int uu = 0; uu < H_; uu += 4) {
      float4 y4 = *(const float4*)(yrow + uu);
#pragma unroll
      for (int m = 0; m < 8; ++m) {
        const float* wr = cw + ov[m] * H_ + uu;
        acc[m] += wr[0] * y4.x + wr[1] * y4.y + wr[2] * y4.z + wr[3] * y4.w;
      }
    }
#pragma unroll
    for (int m = 0; m < 8; ++m) {
      int o = w + 32 * og + 4 * m;
      if (o < 81 && acc[m] > best) {
        best = acc[m];
        bi = o;
      }
    }
  }
  __shared__ float sv[4][64];
  __shared__ int si[4][64];
  sv[w][lane] = best;
  si[w][lane] = bi;
  __syncthreads();
  if (tid < 64) {
    float bv = sv[0][tid];
    int bo = si[0][tid];
#pragma unroll
    for (int ww = 1; ww < 4; ++ww) {
      float v = sv[ww][tid];
      int o = si[ww][tid];
      if (v > bv || (v == bv && o < bo)) {
        bv = v;
        bo = o;
      }
    }
    out[tid * T_ + t] = bo;
  }
}

extern "C" void kernel_launch(void* const* d_in, const int* in_sizes, int n_in,
                              void* d_out, int out_size, void* d_ws,
                              size_t ws_size, hipStream_t stream) {
  const float* x = (const float*)d_in[0];
  const float* Wih0 = (const float*)d_in[1];
  const float* Whh0 = (const float*)d_in[2];
  const float* b0 = (const float*)d_in[3];
  const float* Wih12 = (const float*)d_in[4];
  const float* Whh12 = (const float*)d_in[5];
  const float* b12 = (const float*)d_in[6];
  const float* cw = (const float*)d_in[7];
  const float* cb = (const float*)d_in[8];
  int* out = (int*)d_out;
  char* wsb = (char*)d_ws;

  // zero flags + h ring (ws is re-poisoned 0xAA before every launch)
  hipMemsetAsync(wsb, 0, OFF_H + 786432, stream);
  transpose_x<<<dim3(16, 64, 1), dim3(64, 1, 1), 0, stream>>>(
      x, (float*)(wsb + OFF_XT));
  lstm_persistent<<<dim3(NBLK, 1, 1), dim3(NTHR, 1, 1), 0, stream>>>(
      Wih0, Whh0, b0, Wih12, Whh12, b12, wsb);
  conv_argmax<<<dim3(T_, 1, 1), dim3(256, 1, 1), 0, stream>>>(
      (const float*)(wsb + OFF_YS), cw, cb, out);
}

// Round 5
// 18411.481 us; speedup vs baseline: 13.5202x; 1.3769x over previous
//
#include <hip/hip_runtime.h>

// Encoder: 3-layer bidirectional-weights LSTM (both dirs scan forward per the
// reference), H=256, B=64, T=1024, then 256->81 linear + argmax (softmax is
// monotone -> dead code).
//
// R5: R4 numerics kept bit-identical. Coherence redesign:
//  - h-ring / ys exchange via explicit LLC-coherent accesses (sc0 sc1 bypass,
//    inline asm): MALL is the coherence point -> NO fences needed at all.
//  - grid barrier = relaxed LLC atomics only (no wbl2, no inv): weights and x
//    stay resident in L1/L2 across all 1026 ticks.
//  - act (h) loads batched 4-deep per asm block (offset:1024/2048/3072) for MLP.
//  - dropped the redundant per-task trailing __syncthreads before grid barrier.

#define H_ 256
#define B_ 64
#define T_ 1024
#define NBLK 256
#define NTHR 1024
#define HBUF 98304     // floats per h ring buffer: 6 cells * 16384
#define NTICK 1026

// ws byte offsets
#define OFF_GEN  0
#define OFF_ROOT 64
#define OFF_CNT  128          // 8 counters, 64B apart
#define OFF_H    4096         // hbuf[2][6][16384] floats = 786432 B
#define OFF_XT   1048576      // xT2[1024][16][64][4] floats = 16 MB
#define OFF_YS   17825792     // ys[1024][64][256] floats = 64 MB

__device__ __forceinline__ float sigf(float x) {
  return 1.0f / (1.0f + __expf(-x));
}
__device__ __forceinline__ float tanhf_(float x) {
  float e = __expf(-2.0f * fabsf(x));
  float r = (1.0f - e) / (1.0f + e);
  return x >= 0.0f ? r : -r;
}

// ---- LLC-coherent (bypass L1/L2) access helpers ----
__device__ __forceinline__ void llc_ld1(const float4* p, float4& r) {
  asm volatile(
      "global_load_dwordx4 %0, %1, off sc0 sc1\n\t"
      "s_waitcnt vmcnt(0)"
      : "=v"(r)
      : "v"(p)
      : "memory");
}
// 4 consecutive k4 rows (1024 B apart), one drain: 4-deep MLP
__device__ __forceinline__ void llc_ld4(const float4* p, float4& r0, float4& r1,
                                        float4& r2, float4& r3) {
  asm volatile(
      "global_load_dwordx4 %0, %4, off sc0 sc1\n\t"
      "global_load_dwordx4 %1, %4, off offset:1024 sc0 sc1\n\t"
      "global_load_dwordx4 %2, %4, off offset:2048 sc0 sc1\n\t"
      "global_load_dwordx4 %3, %4, off offset:3072 sc0 sc1\n\t"
      "s_waitcnt vmcnt(0)"
      : "=&v"(r0), "=&v"(r1), "=&v"(r2), "=&v"(r3)
      : "v"(p)
      : "memory");
}
__device__ __forceinline__ void llc_st1(float* p, float v) {
  asm volatile(
      "global_store_dword %0, %1, off sc0 sc1\n\t"
      "s_waitcnt vmcnt(0)" ::"v"(p),
      "v"(v)
      : "memory");
}
__device__ __forceinline__ void llc_st2(float* p1, float v1, float* p2, float v2) {
  asm volatile(
      "global_store_dword %0, %1, off sc0 sc1\n\t"
      "global_store_dword %2, %3, off sc0 sc1\n\t"
      "s_waitcnt vmcnt(0)" ::"v"(p1),
      "v"(v1), "v"(p2), "v"(v2)
      : "memory");
}

// ---------------- x transpose: x[b][k][t] -> xT2[t][k>>2][b][k&3] ----------------
__global__ __launch_bounds__(64) void transpose_x(const float* __restrict__ x,
                                                  float* __restrict__ xT) {
  __shared__ float tile[64][65];
  const int k = blockIdx.y;
  const int t0 = blockIdx.x * 64;
  const int lane = threadIdx.x;
  for (int bi = 0; bi < 64; ++bi)
    tile[bi][lane] = x[bi * 65536 + k * 1024 + t0 + lane];
  __syncthreads();
  for (int ti = 0; ti < 64; ++ti)
    xT[(size_t)(t0 + ti) * 4096 + (k >> 2) * 256 + lane * 4 + (k & 3)] =
        tile[lane][ti];
}

// ---------------- 8-row FMA body for one k4 (order matches R4 bitwise) --------
__device__ __forceinline__ void body8(float* __restrict__ acc, const float4 av,
                                      const float* __restrict__ wb,
                                      const int ws, const int u0, const int k4) {
#pragma unroll
  for (int a = 0; a < 8; ++a) {
    const float* wp =
        wb + (size_t)((a & 3) * 256 + u0 + (a >> 2)) * ws + k4 * 4;
    float4 wq = *(const float4*)wp;
    acc[a] += wq.x * av.x + wq.y * av.y + wq.z * av.z + wq.w * av.w;
  }
}

// segment driver: k4 ascending, batches of 4 then tail (same fp order as R4)
__device__ __forceinline__ void seg8(float* __restrict__ acc, const int a,
                                     const int b, const float4* __restrict__ act,
                                     const int actOff,  // subtract from k4
                                     const float* __restrict__ wb, const int ws,
                                     const int u0, const int lane,
                                     const bool byp) {
  int k4 = a;
  for (; k4 + 4 <= b; k4 += 4) {
    const float4* p = act + (size_t)(k4 - actOff) * 64 + lane;
    float4 v0, v1, v2, v3;
    if (byp) {
      llc_ld4(p, v0, v1, v2, v3);
    } else {
      v0 = p[0];
      v1 = p[64];
      v2 = p[128];
      v3 = p[192];
    }
    body8(acc, v0, wb, ws, u0, k4 - actOff + 0);
    body8(acc, v1, wb, ws, u0, k4 - actOff + 1);
    body8(acc, v2, wb, ws, u0, k4 - actOff + 2);
    body8(acc, v3, wb, ws, u0, k4 - actOff + 3);
  }
  for (; k4 < b; ++k4) {
    const float4* p = act + (size_t)(k4 - actOff) * 64 + lane;
    float4 v;
    if (byp)
      llc_ld1(p, v);
    else
      v = *p;
    body8(acc, v, wb, ws, u0, k4 - actOff);
  }
}

// ---------------- one gate task: 8 rows (2 units x 4 gates), K4 k4-groups ----
__device__ __forceinline__ void task8(
    const int w, const int lane, const int tid, const int u0,
    const int K4, const int nA4,
    const float4* __restrict__ actA, const bool bypA,  // k4 in [0, nA4)
    const float4* __restrict__ actB, const bool bypB,  // k4 in [nA4, K4)
    const float* __restrict__ wAb, const int wAs,
    const float* __restrict__ wBb, const int wBs,
    const float* __restrict__ bias,    // bias[g*256 + u]
    float* __restrict__ cst2,          // LDS [2][64]
    float* __restrict__ hcell,         // h write base for this cell (LLC)
    float* __restrict__ ysrow,         // ys + t*16384 or nullptr (LLC)
    float (*red)[64][12], const bool lastTask) {
  const int slice = K4 >> 4;           // K4/16 waves
  const int lo = w * slice, hi = lo + slice;
  float acc[8] = {0.f, 0.f, 0.f, 0.f, 0.f, 0.f, 0.f, 0.f};

  // segment A: k4 in [lo, min(hi,nA4))
  {
    const int b4 = hi < nA4 ? hi : nA4;
    if (lo < b4) seg8(acc, lo, b4, actA, 0, wAb, wAs, u0, lane, bypA);
  }
  // segment B: k4 in [max(lo,nA4), hi)
  {
    const int a4 = lo > nA4 ? lo : nA4;
    if (a4 < hi) seg8(acc, a4, hi, actB, nA4, wBb, wBs, u0, lane, bypB);
  }

  // 8 partials -> 2x b128 LDS writes
  *(float4*)&red[w][lane][0] = make_float4(acc[0], acc[1], acc[2], acc[3]);
  *(float4*)&red[w][lane][4] = make_float4(acc[4], acc[5], acc[6], acc[7]);
  __syncthreads();

  if (tid < 128) {
    const int uu = tid >> 6, b = tid & 63;
    // bias FIRST, then wave partials ascending (bit-identical to R2/R4)
    float gi = bias[0 * 256 + u0 + uu];
    float gf = bias[1 * 256 + u0 + uu];
    float gg = bias[2 * 256 + u0 + uu];
    float go = bias[3 * 256 + u0 + uu];
#pragma unroll
    for (int ww = 0; ww < 16; ++ww) {
      float4 s = *(const float4*)&red[ww][b][uu * 4];
      gi += s.x; gf += s.y; gg += s.z; go += s.w;
    }
    float iv = sigf(gi), fv = sigf(gf), gv = tanhf_(gg), ov = sigf(go);
    float c = fv * cst2[uu * 64 + b] + iv * gv;
    cst2[uu * 64 + b] = c;
    float h = ov * tanhf_(c);
    const int u = u0 + uu;
    float* hp = hcell + (u >> 2) * 256 + b * 4 + (u & 3);
    if (ysrow)
      llc_st2(hp, h, ysrow + b * 256 + u, h);
    else
      llc_st1(hp, h);
  }
  if (!lastTask) __syncthreads();  // grid barrier's sync covers the last task
}

// ---------------- persistent skewed LSTM ----------------
__global__ __launch_bounds__(NTHR, 1) void lstm_persistent(
    const float* __restrict__ Wih0, const float* __restrict__ Whh0,
    const float* __restrict__ b0, const float* __restrict__ Wih12,
    const float* __restrict__ Whh12, const float* __restrict__ b12, char* wsb) {
  unsigned* gen = (unsigned*)(wsb + OFF_GEN);
  unsigned* root = (unsigned*)(wsb + OFF_ROOT);
  float* hb = (float*)(wsb + OFF_H);
  const float* xT = (const float*)(wsb + OFF_XT);
  float* ys = (float*)(wsb + OFF_YS);

  __shared__ float red[16][64][12];   // 48 KB, b128-friendly (pad 12)
  __shared__ float cst[3][2][64];     // per-layer c state

  const int bid = blockIdx.x;
  const int tid = threadIdx.x;
  const int lane = tid & 63;
  const int w = __builtin_amdgcn_readfirstlane(tid >> 6);  // uniform wave id
  const int d = bid >> 7;          // direction 0/1
  const int u0 = (bid & 127) * 2;  // unit tile base

  if (tid < 384) ((float*)cst)[tid] = 0.f;
  __syncthreads();

  unsigned* mycnt = (unsigned*)(wsb + OFF_CNT + (size_t)(bid & 7) * 64);

  for (unsigned tick = 0; tick < NTICK; ++tick) {
    const float* R = hb + ((tick + 1) & 1) * HBUF;  // produced last tick
    float* W = hb + (tick & 1) * HBUF;              // produced this tick
    const float4* Rf4 = (const float4*)R;

    const bool has0 = tick < 1024;
    const bool has1 = tick >= 1 && tick < 1025;
    const bool has2 = tick >= 2;

    // Layer 0 (cell d): t = tick; K4 = 16 (x, cached) + 64 (rec h, LLC)
    if (has0) {
      task8(w, lane, tid, u0, 80, 16,
            (const float4*)xT + (size_t)tick * 1024, false,
            Rf4 + (size_t)d * 4096, true,
            Wih0 + (size_t)d * 65536, 64,
            Whh0 + (size_t)d * 262144, 256,
            b0 + d * 1024, &cst[0][0][0], W + (size_t)d * 16384, nullptr, red,
            !(has1 || has2));
    }
    // Layer 1 (cell 2+d): t = tick-1; K4 = 128 (cells 0,1) + 64 (rec)
    if (has1) {
      task8(w, lane, tid, u0, 192, 128,
            Rf4, true,
            Rf4 + (size_t)(2 + d) * 4096, true,
            Wih12 + (size_t)d * 524288, 512,
            Whh12 + (size_t)d * 262144, 256,
            b12 + d * 1024, &cst[1][0][0], W + (size_t)(2 + d) * 16384, nullptr,
            red, !has2);
    }
    // Layer 2 (cell 4+d): t = tick-2; K4 = 128 (cells 2,3) + 64 (rec)
    if (has2) {
      const int t = (int)tick - 2;
      task8(w, lane, tid, u0, 192, 128,
            Rf4 + (size_t)2 * 4096, true,
            Rf4 + (size_t)(4 + d) * 4096, true,
            Wih12 + (size_t)(2 + d) * 524288, 512,
            Whh12 + (size_t)(2 + d) * 262144, 256,
            b12 + (2 + d) * 1024, &cst[2][0][0], W + (size_t)(4 + d) * 16384,
            (d == 1) ? (ys + (size_t)t * 16384) : nullptr, red, true);
    }

    // -------- grid barrier: pure relaxed LLC atomics, NO fences --------
    // (h/ys already LLC-visible: bypass stores drained before this point)
    __syncthreads();
    if (tid == 0) {
      unsigned old = __hip_atomic_fetch_add(mycnt, 1u, __ATOMIC_RELAXED,
                                            __HIP_MEMORY_SCOPE_AGENT);
      if (old == (tick + 1) * (NBLK / 8) - 1) {
        unsigned r = __hip_atomic_fetch_add(root, 1u, __ATOMIC_RELAXED,
                                            __HIP_MEMORY_SCOPE_AGENT);
        if (r == (tick + 1) * 8 - 1) {
          __hip_atomic_store(gen, tick + 1, __ATOMIC_RELAXED,
                             __HIP_MEMORY_SCOPE_AGENT);
        }
      }
      while (__hip_atomic_load(gen, __ATOMIC_RELAXED, __HIP_MEMORY_SCOPE_AGENT) <
             tick + 1) {
        __builtin_amdgcn_s_sleep(2);
      }
    }
    __syncthreads();
  }
}

// ---------------- conv(256->81) + argmax ----------------
__global__ __launch_bounds__(256) void conv_argmax(const float* __restrict__ yst,
                                                   const float* __restrict__ cw,
                                                   const float* __restrict__ cb,
                                                   int* __restrict__ out) {
  const int t = blockIdx.x;
  const int tid = threadIdx.x, lane = tid & 63, w = tid >> 6;
  const float* yrow = yst + (size_t)t * (B_ * H_) + lane * H_;
  float best = -3.4e38f;
  int bi = 0;
  for (int og = 0; og < 3; ++og) {
    float acc[8];
    int ov[8];
#pragma unroll
    for (int m = 0; m < 8; ++m) {
      int o = w + 32 * og + 4 * m;
      ov[m] = (o < 81) ? o : 80;
      acc[m] = (o < 81) ? cb[o] : -3.4e38f;
    }
    for (int uu = 0; uu < H_; uu += 4) {
      float4 y4 = *(const float4*)(yrow + uu);
#pragma unroll
      for (int m = 0; m < 8; ++m) {
        const float* wr = cw + ov[m] * H_ + uu;
        acc[m] += wr[0] * y4.x + wr[1] * y4.y + wr[2] * y4.z + wr[3] * y4.w;
      }
    }
#pragma unroll
    for (int m = 0; m < 8; ++m) {
      int o = w + 32 * og + 4 * m;
      if (o < 81 && acc[m] > best) {
        best = acc[m];
        bi = o;
      }
    }
  }
  __shared__ float sv[4][64];
  __shared__ int si[4][64];
  sv[w][lane] = best;
  si[w][lane] = bi;
  __syncthreads();
  if (tid < 64) {
    float bv = sv[0][tid];
    int bo = si[0][tid];
#pragma unroll
    for (int ww = 1; ww < 4; ++ww) {
      float v = sv[ww][tid];
      int o = si[ww][tid];
      if (v > bv || (v == bv && o < bo)) {
        bv = v;
        bo = o;
      }
    }
    out[tid * T_ + t] = bo;
  }
}

extern "C" void kernel_launch(void* const* d_in, const int* in_sizes, int n_in,
                              void* d_out, int out_size, void* d_ws,
                              size_t ws_size, hipStream_t stream) {
  const float* x = (const float*)d_in[0];
  const float* Wih0 = (const float*)d_in[1];
  const float* Whh0 = (const float*)d_in[2];
  const float* b0 = (const float*)d_in[3];
  const float* Wih12 = (const float*)d_in[4];
  const float* Whh12 = (const float*)d_in[5];
  const float* b12 = (const float*)d_in[6];
  const float* cw = (const float*)d_in[7];
  const float* cb = (const float*)d_in[8];
  int* out = (int*)d_out;
  char* wsb = (char*)d_ws;

  // zero flags + h ring (ws is re-poisoned 0xAA before every launch)
  hipMemsetAsync(wsb, 0, OFF_H + 786432, stream);
  transpose_x<<<dim3(16, 64, 1), dim3(64, 1, 1), 0, stream>>>(
      x, (float*)(wsb + OFF_XT));
  lstm_persistent<<<dim3(NBLK, 1, 1), dim3(NTHR, 1, 1), 0, stream>>>(
      Wih0, Whh0, b0, Wih12, Whh12, b12, wsb);
  conv_argmax<<<dim3(T_, 1, 1), dim3(256, 1, 1), 0, stream>>>(
      (const float*)(wsb + OFF_YS), cw, cb, out);
}

// Round 7
// 18387.451 us; speedup vs baseline: 13.5379x; 1.0013x over previous
//
#include <hip/hip_runtime.h>

// Encoder: 3-layer bidirectional-weights LSTM (both dirs scan forward per the
// reference), H=256, B=64, T=1024, then 256->81 linear + argmax (softmax is
// monotone -> dead code).
//
// R6b: R5 (LLC-coherent h exchange via fused issue+wait asm helpers, fence-free
// relaxed barrier) + ALL weights staged once into LDS ([k4][8rows][4], 59 KB):
// weight reads become wave-uniform ds_read_b128 broadcasts (lgkm pipe) and the
// per-k4 weight address VALU (~6.4us/tick in R5) disappears. FMA order
// bit-identical to R4/R5 (ascending k4, same chains, bias-first epilogue).
// (R6's split issue/wait asm with tied float4 operands doesn't compile: LLVM
// "tied indirect register inputs" -- fused helpers retained instead.)

#define H_ 256
#define B_ 64
#define T_ 1024
#define NBLK 256
#define NTHR 1024
#define HBUF 98304     // floats per h ring buffer: 6 cells * 16384
#define NTICK 1026

// ws byte offsets
#define OFF_GEN  0
#define OFF_ROOT 64
#define OFF_CNT  128          // 8 counters, 64B apart
#define OFF_H    4096         // hbuf[2][6][16384] floats = 786432 B
#define OFF_XT   1048576      // xT2[1024][16][64][4] floats = 16 MB
#define OFF_YS   17825792     // ys[1024][64][256] floats = 64 MB

__device__ __forceinline__ float sigf(float x) {
  return 1.0f / (1.0f + __expf(-x));
}
__device__ __forceinline__ float tanhf_(float x) {
  float e = __expf(-2.0f * fabsf(x));
  float r = (1.0f - e) / (1.0f + e);
  return x >= 0.0f ? r : -r;
}

// ---- LLC-coherent (bypass L1/L2) access helpers (R5-proven) ----
__device__ __forceinline__ void llc_ld1(const float4* p, float4& r) {
  asm volatile(
      "global_load_dwordx4 %0, %1, off sc0 sc1\n\t"
      "s_waitcnt vmcnt(0)"
      : "=v"(r)
      : "v"(p)
      : "memory");
}
// 4 consecutive k4 rows (1024 B apart), one drain: 4-deep MLP
__device__ __forceinline__ void llc_ld4(const float4* p, float4& r0, float4& r1,
                                        float4& r2, float4& r3) {
  asm volatile(
      "global_load_dwordx4 %0, %4, off sc0 sc1\n\t"
      "global_load_dwordx4 %1, %4, off offset:1024 sc0 sc1\n\t"
      "global_load_dwordx4 %2, %4, off offset:2048 sc0 sc1\n\t"
      "global_load_dwordx4 %3, %4, off offset:3072 sc0 sc1\n\t"
      "s_waitcnt vmcnt(0)"
      : "=&v"(r0), "=&v"(r1), "=&v"(r2), "=&v"(r3)
      : "v"(p)
      : "memory");
}
__device__ __forceinline__ void llc_st1(float* p, float v) {
  asm volatile(
      "global_store_dword %0, %1, off sc0 sc1\n\t"
      "s_waitcnt vmcnt(0)" ::"v"(p),
      "v"(v)
      : "memory");
}
__device__ __forceinline__ void llc_st2(float* p1, float v1, float* p2, float v2) {
  asm volatile(
      "global_store_dword %0, %1, off sc0 sc1\n\t"
      "global_store_dword %2, %3, off sc0 sc1\n\t"
      "s_waitcnt vmcnt(0)" ::"v"(p1),
      "v"(v1), "v"(p2), "v"(v2)
      : "memory");
}

// ---------------- x transpose: x[b][k][t] -> xT2[t][k>>2][b][k&3] ----------------
__global__ __launch_bounds__(64) void transpose_x(const float* __restrict__ x,
                                                  float* __restrict__ xT) {
  __shared__ float tile[64][65];
  const int k = blockIdx.y;
  const int t0 = blockIdx.x * 64;
  const int lane = threadIdx.x;
  for (int bi = 0; bi < 64; ++bi)
    tile[bi][lane] = x[bi * 65536 + k * 1024 + t0 + lane];
  __syncthreads();
  for (int ti = 0; ti < 64; ++ti)
    xT[(size_t)(t0 + ti) * 4096 + (k >> 2) * 256 + lane * 4 + (k & 3)] =
        tile[lane][ti];
}

// ---------------- 8-row FMA body for one k4 (order matches R4/R5 bitwise) ----
// weights from LDS: wl[k4*32 + a*4 .. +3]  (wave-uniform ds_read_b128 broadcast)
__device__ __forceinline__ void body8(float* __restrict__ acc, const float4 av,
                                      const float* __restrict__ wl,
                                      const int k4) {
  const float* wp = wl + (size_t)k4 * 32;
#pragma unroll
  for (int a = 0; a < 8; ++a) {
    float4 wq = *(const float4*)(wp + a * 4);
    acc[a] += wq.x * av.x + wq.y * av.y + wq.z * av.z + wq.w * av.w;
  }
}

// segment driver: k4 ascending, batches of 4 then tail (same fp order as R4/R5)
// k4 is task-global; act indexed by (k4 - actOff); weights by task-global k4.
__device__ __forceinline__ void seg8(float* __restrict__ acc, const int a,
                                     const int b, const float4* __restrict__ act,
                                     const int actOff,
                                     const float* __restrict__ wl,
                                     const int lane, const bool byp) {
  int k4 = a;
  for (; k4 + 4 <= b; k4 += 4) {
    const float4* p = act + (size_t)(k4 - actOff) * 64 + lane;
    float4 v0, v1, v2, v3;
    if (byp) {
      llc_ld4(p, v0, v1, v2, v3);
    } else {
      v0 = p[0];
      v1 = p[64];
      v2 = p[128];
      v3 = p[192];
    }
    body8(acc, v0, wl, k4 + 0);
    body8(acc, v1, wl, k4 + 1);
    body8(acc, v2, wl, k4 + 2);
    body8(acc, v3, wl, k4 + 3);
  }
  for (; k4 < b; ++k4) {
    const float4* p = act + (size_t)(k4 - actOff) * 64 + lane;
    float4 v;
    if (byp)
      llc_ld1(p, v);
    else
      v = *p;
    body8(acc, v, wl, k4);
  }
}

// ---------------- one gate task: 8 rows (2 units x 4 gates), K4 k4-groups ----
__device__ __forceinline__ void task8(
    const int w, const int lane, const int tid, const int u0,
    const int K4, const int nA4,
    const float4* __restrict__ actA, const bool bypA,  // k4 in [0, nA4)
    const float4* __restrict__ actB, const bool bypB,  // k4 in [nA4, K4)
    const float* __restrict__ wl,      // LDS weight base for this task
    const float* __restrict__ bias,    // bias[g*256 + u]
    float* __restrict__ cst2,          // LDS [2][64]
    float* __restrict__ hcell,         // h write base for this cell (LLC)
    float* __restrict__ ysrow,         // ys + t*16384 or nullptr (LLC)
    float (*red)[64][12], const bool lastTask) {
  const int slice = K4 >> 4;           // K4/16 waves
  const int lo = w * slice, hi = lo + slice;
  float acc[8] = {0.f, 0.f, 0.f, 0.f, 0.f, 0.f, 0.f, 0.f};

  // segment A: k4 in [lo, min(hi,nA4))
  {
    const int b4 = hi < nA4 ? hi : nA4;
    if (lo < b4) seg8(acc, lo, b4, actA, 0, wl, lane, bypA);
  }
  // segment B: k4 in [max(lo,nA4), hi)
  {
    const int a4 = lo > nA4 ? lo : nA4;
    if (a4 < hi) seg8(acc, a4, hi, actB, nA4, wl, lane, bypB);
  }

  // 8 partials -> 2x b128 LDS writes
  *(float4*)&red[w][lane][0] = make_float4(acc[0], acc[1], acc[2], acc[3]);
  *(float4*)&red[w][lane][4] = make_float4(acc[4], acc[5], acc[6], acc[7]);
  __syncthreads();

  if (tid < 128) {
    const int uu = tid >> 6, b = tid & 63;
    // bias FIRST, then wave partials ascending (bit-identical to R2/R4/R5)
    float gi = bias[0 * 256 + u0 + uu];
    float gf = bias[1 * 256 + u0 + uu];
    float gg = bias[2 * 256 + u0 + uu];
    float go = bias[3 * 256 + u0 + uu];
#pragma unroll
    for (int ww = 0; ww < 16; ++ww) {
      float4 s = *(const float4*)&red[ww][b][uu * 4];
      gi += s.x; gf += s.y; gg += s.z; go += s.w;
    }
    float iv = sigf(gi), fv = sigf(gf), gv = tanhf_(gg), ov = sigf(go);
    float c = fv * cst2[uu * 64 + b] + iv * gv;
    cst2[uu * 64 + b] = c;
    float h = ov * tanhf_(c);
    const int u = u0 + uu;
    float* hp = hcell + (u >> 2) * 256 + b * 4 + (u & 3);
    if (ysrow)
      llc_st2(hp, h, ysrow + b * 256 + u, h);
    else
      llc_st1(hp, h);
  }
  if (!lastTask) __syncthreads();
}

// ---------------- persistent skewed LSTM ----------------
__global__ __launch_bounds__(NTHR, 1) void lstm_persistent(
    const float* __restrict__ Wih0, const float* __restrict__ Whh0,
    const float* __restrict__ b0, const float* __restrict__ Wih12,
    const float* __restrict__ Whh12, const float* __restrict__ b12, char* wsb) {
  unsigned* gen = (unsigned*)(wsb + OFF_GEN);
  unsigned* root = (unsigned*)(wsb + OFF_ROOT);
  float* hb = (float*)(wsb + OFF_H);
  const float* xT = (const float*)(wsb + OFF_XT);
  float* ys = (float*)(wsb + OFF_YS);

  __shared__ float red[16][64][12];   // 48 KB
  __shared__ float cst[3][2][64];     // per-layer c state (1.5 KB)
  __shared__ float wlds[14848];       // 59 KB: per-task [k4][8 rows][4]

  const int bid = blockIdx.x;
  const int tid = threadIdx.x;
  const int lane = tid & 63;
  const int w = __builtin_amdgcn_readfirstlane(tid >> 6);  // uniform wave id
  const int d = bid >> 7;          // direction 0/1
  const int u0 = (bid & 127) * 2;  // unit tile base

  if (tid < 384) ((float*)cst)[tid] = 0.f;

  // ---- stage all weights for this block into LDS (once) ----
  auto stage = [&](const float* wA, int wAs, const float* wB, int wBs,
                   int K4s, int NA4s, float* dst) {
    const int nq = K4s * 8;
    for (int idx = tid; idx < nq; idx += NTHR) {
      const int a = idx / K4s;
      const int k4 = idx - a * K4s;
      const int row = (a & 3) * 256 + u0 + (a >> 2);
      const float* src = (k4 < NA4s) ? (wA + (size_t)row * wAs + k4 * 4)
                                     : (wB + (size_t)row * wBs + (k4 - NA4s) * 4);
      float4 q = *(const float4*)src;
      *(float4*)(dst + ((size_t)k4 * 8 + a) * 4) = q;
    }
  };
  stage(Wih0 + (size_t)d * 65536, 64, Whh0 + (size_t)d * 262144, 256, 80, 16,
        wlds);
  stage(Wih12 + (size_t)d * 524288, 512, Whh12 + (size_t)d * 262144, 256, 192,
        128, wlds + 2560);
  stage(Wih12 + (size_t)(2 + d) * 524288, 512,
        Whh12 + (size_t)(2 + d) * 262144, 256, 192, 128, wlds + 8704);
  __syncthreads();

  unsigned* mycnt = (unsigned*)(wsb + OFF_CNT + (size_t)(bid & 7) * 64);

  for (unsigned tick = 0; tick < NTICK; ++tick) {
    const float* R = hb + ((tick + 1) & 1) * HBUF;  // produced last tick
    float* W = hb + (tick & 1) * HBUF;              // produced this tick
    const float4* Rf4 = (const float4*)R;

    const bool has0 = tick < 1024;
    const bool has1 = tick >= 1 && tick < 1025;
    const bool has2 = tick >= 2;

    // Layer 0 (cell d): t = tick; K4 = 16 (x, cached) + 64 (rec h, LLC)
    if (has0) {
      task8(w, lane, tid, u0, 80, 16,
            (const float4*)xT + (size_t)tick * 1024, false,
            Rf4 + (size_t)d * 4096, true,
            wlds, b0 + d * 1024, &cst[0][0][0],
            W + (size_t)d * 16384, nullptr, red, !(has1 || has2));
    }
    // Layer 1 (cell 2+d): t = tick-1; K4 = 128 (cells 0,1) + 64 (rec)
    if (has1) {
      task8(w, lane, tid, u0, 192, 128,
            Rf4, true,
            Rf4 + (size_t)(2 + d) * 4096, true,
            wlds + 2560, b12 + d * 1024, &cst[1][0][0],
            W + (size_t)(2 + d) * 16384, nullptr, red, !has2);
    }
    // Layer 2 (cell 4+d): t = tick-2; K4 = 128 (cells 2,3) + 64 (rec)
    if (has2) {
      const int t = (int)tick - 2;
      task8(w, lane, tid, u0, 192, 128,
            Rf4 + (size_t)2 * 4096, true,
            Rf4 + (size_t)(4 + d) * 4096, true,
            wlds + 8704, b12 + (2 + d) * 1024, &cst[2][0][0],
            W + (size_t)(4 + d) * 16384,
            (d == 1) ? (ys + (size_t)t * 16384) : nullptr, red, true);
    }

    // -------- grid barrier: pure relaxed LLC atomics, NO fences --------
    __syncthreads();
    if (tid == 0) {
      unsigned old = __hip_atomic_fetch_add(mycnt, 1u, __ATOMIC_RELAXED,
                                            __HIP_MEMORY_SCOPE_AGENT);
      if (old == (tick + 1) * (NBLK / 8) - 1) {
        unsigned r = __hip_atomic_fetch_add(root, 1u, __ATOMIC_RELAXED,
                                            __HIP_MEMORY_SCOPE_AGENT);
        if (r == (tick + 1) * 8 - 1) {
          __hip_atomic_store(gen, tick + 1, __ATOMIC_RELAXED,
                             __HIP_MEMORY_SCOPE_AGENT);
        }
      }
      while (__hip_atomic_load(gen, __ATOMIC_RELAXED, __HIP_MEMORY_SCOPE_AGENT) <
             tick + 1) {
        __builtin_amdgcn_s_sleep(2);
      }
    }
    __syncthreads();
  }
}

// ---------------- conv(256->81) + argmax ----------------
__global__ __launch_bounds__(256) void conv_argmax(const float* __restrict__ yst,
                                                   const float* __restrict__ cw,
                                                   const float* __restrict__ cb,
                                                   int* __restrict__ out) {
  const int t = blockIdx.x;
  const int tid = threadIdx.x, lane = tid & 63, w = tid >> 6;
  const float* yrow = yst + (size_t)t * (B_ * H_) + lane * H_;
  float best = -3.4e38f;
  int bi = 0;
  for (int og = 0; og < 3; ++og) {
    float acc[8];
    int ov[8];
#pragma unroll
    for (int m = 0; m < 8; ++m) {
      int o = w + 32 * og + 4 * m;
      ov[m] = (o < 81) ? o : 80;
      acc[m] = (o < 81) ? cb[o] : -3.4e38f;
    }
    for (int uu = 0; uu < H_; uu += 4) {
      float4 y4 = *(const float4*)(yrow + uu);
#pragma unroll
      for (int m = 0; m < 8; ++m) {
        const float* wr = cw + ov[m] * H_ + uu;
        acc[m] += wr[0] * y4.x + wr[1] * y4.y + wr[2] * y4.z + wr[3] * y4.w;
      }
    }
#pragma unroll
    for (int m = 0; m < 8; ++m) {
      int o = w + 32 * og + 4 * m;
      if (o < 81 && acc[m] > best) {
        best = acc[m];
        bi = o;
      }
    }
  }
  __shared__ float sv[4][64];
  __shared__ int si[4][64];
  sv[w][lane] = best;
  si[w][lane] = bi;
  __syncthreads();
  if (tid < 64) {
    float bv = sv[0][tid];
    int bo = si[0][tid];
#pragma unroll
    for (int ww = 1; ww < 4; ++ww) {
      float v = sv[ww][tid];
      int o = si[ww][tid];
      if (v > bv || (v == bv && o < bo)) {
        bv = v;
        bo = o;
      }
    }
    out[tid * T_ + t] = bo;
  }
}

extern "C" void kernel_launch(void* const* d_in, const int* in_sizes, int n_in,
                              void* d_out, int out_size, void* d_ws,
                              size_t ws_size, hipStream_t stream) {
  const float* x = (const float*)d_in[0];
  const float* Wih0 = (const float*)d_in[1];
  const float* Whh0 = (const float*)d_in[2];
  const float* b0 = (const float*)d_in[3];
  const float* Wih12 = (const float*)d_in[4];
  const float* Whh12 = (const float*)d_in[5];
  const float* b12 = (const float*)d_in[6];
  const float* cw = (const float*)d_in[7];
  const float* cb = (const float*)d_in[8];
  int* out = (int*)d_out;
  char* wsb = (char*)d_ws;

  // zero flags + h ring (ws is re-poisoned 0xAA before every launch)
  hipMemsetAsync(wsb, 0, OFF_H + 786432, stream);
  transpose_x<<<dim3(16, 64, 1), dim3(64, 1, 1), 0, stream>>>(
      x, (float*)(wsb + OFF_XT));
  lstm_persistent<<<dim3(NBLK, 1, 1), dim3(NTHR, 1, 1), 0, stream>>>(
      Wih0, Whh0, b0, Wih12, Whh12, b12, wsb);
  conv_argmax<<<dim3(T_, 1, 1), dim3(256, 1, 1), 0, stream>>>(
      (const float*)(wsb + OFF_YS), cw, cb, out);
}